// Round 1
// baseline (515.732 us; speedup 1.0000x reference)
//
#include <hip/hip_runtime.h>
#include <math.h>

// ---------------------------------------------------------------------------
// TaggingQuantizer: cosine-distance VQ assignment + loss + pos/neg reorder.
//   z: (65536, 256) f32,  W: (1024, 256) f32
//   out: emb (1024*256) | label (1024) | loss (1)   all f32, flat-concat.
// ---------------------------------------------------------------------------

#define N_E   1024
#define E_DIM 256
#define N_TOK 65536
#define BETA  0.25f

// ws layout (bytes):
//   [0,      4096)   float inv_norm[1024]
//   [4096,   266240) int   idx[65536]
//   [266240, 270336) int   mask[1024]
//   [270336, 274432) int   rank[1024]
//   [274432, 274440) double loss_acc
#define WS_INVNORM 0
#define WS_IDX     4096
#define WS_MASK    266240
#define WS_RANK    270336
#define WS_LACC    274432

// --------------------------------------------------------------------------
// K1: per-code inverse norms; also zero mask + loss accumulator (ws is
// poisoned 0xAA before every timed launch).
// --------------------------------------------------------------------------
__global__ void k_norms(const float* __restrict__ W, float* __restrict__ inv_norm,
                        int* __restrict__ mask, double* __restrict__ lacc) {
    const int e = blockIdx.x;        // 1024 blocks
    const int lane = threadIdx.x;    // 64 threads = 1 wave
    const float4 v = reinterpret_cast<const float4*>(W + (size_t)e * E_DIM)[lane];
    float s = v.x * v.x + v.y * v.y + v.z * v.z + v.w * v.w;
#pragma unroll
    for (int off = 32; off > 0; off >>= 1) s += __shfl_down(s, off, 64);
    if (lane == 0) {
        inv_norm[e] = 1.0f / sqrtf(s);
        mask[e] = 0;
        if (e == 0) *lacc = 0.0;
    }
}

// --------------------------------------------------------------------------
// K2: fp32 GEMM (z @ Wn^T) fused with per-token argmax.
// Tile: 128 tokens x 128 codes per block, K chunks of 32.
// LDS k-major so fragment reads are ds_read_b128.
// --------------------------------------------------------------------------
#define MT 128
#define NT 128
#define KT 32

__global__ __launch_bounds__(256, 3)
void k_argmax(const float* __restrict__ z, const float* __restrict__ W,
              const float* __restrict__ inv_norm, int* __restrict__ idx_out) {
    __shared__ __align__(16) float As[KT][MT + 4];  // [k][token] , pad 4 keeps 16B align
    __shared__ __align__(16) float Bs[KT][NT + 4];  // [k][code]

    const int t  = threadIdx.x;      // 256 threads
    const int tw = t & 15;           // code group  (8 codes each)
    const int tm = t >> 4;           // token group (8 tokens each)
    const int tok_base = blockIdx.x * MT;

    // staging role: each thread loads 16 consecutive k of one row
    const int srow = t >> 1;         // 0..127
    const int kq   = (t & 1) * 16;   // 0 or 16

    float best_val[8];
    int   best_idx[8];
#pragma unroll
    for (int i = 0; i < 8; i++) { best_val[i] = -3.4e38f; best_idx[i] = 0; }

#pragma unroll 1
    for (int nb = 0; nb < N_E; nb += NT) {
        float acc[8][8];
#pragma unroll
        for (int i = 0; i < 8; i++)
#pragma unroll
            for (int j = 0; j < 8; j++) acc[i][j] = 0.0f;

        const float scale = inv_norm[nb + srow];

#pragma unroll 1
        for (int kc = 0; kc < E_DIM; kc += KT) {
            const float4* zg = reinterpret_cast<const float4*>(
                z + (size_t)(tok_base + srow) * E_DIM + kc + kq);
            const float4* wg = reinterpret_cast<const float4*>(
                W + (size_t)(nb + srow) * E_DIM + kc + kq);
            float4 av[4], bv[4];
#pragma unroll
            for (int j = 0; j < 4; j++) { av[j] = zg[j]; bv[j] = wg[j]; }

            __syncthreads();  // previous chunk's readers done before overwrite
#pragma unroll
            for (int j = 0; j < 4; j++) {
                As[kq + j * 4 + 0][srow] = av[j].x;
                As[kq + j * 4 + 1][srow] = av[j].y;
                As[kq + j * 4 + 2][srow] = av[j].z;
                As[kq + j * 4 + 3][srow] = av[j].w;
                Bs[kq + j * 4 + 0][srow] = bv[j].x * scale;
                Bs[kq + j * 4 + 1][srow] = bv[j].y * scale;
                Bs[kq + j * 4 + 2][srow] = bv[j].z * scale;
                Bs[kq + j * 4 + 3][srow] = bv[j].w * scale;
            }
            __syncthreads();

#pragma unroll 8
            for (int k = 0; k < KT; k++) {
                float a[8], b[8];
#pragma unroll
                for (int i = 0; i < 8; i++) a[i] = As[k][tm * 8 + i];
#pragma unroll
                for (int j = 0; j < 8; j++) b[j] = Bs[k][tw * 8 + j];
#pragma unroll
                for (int i = 0; i < 8; i++)
#pragma unroll
                    for (int j = 0; j < 8; j++)
                        acc[i][j] = fmaf(a[i], b[j], acc[i][j]);
            }
        }

        // fold this code chunk into the running per-token best.
        // ascending j (ascending code) + strict '>' keeps lowest index on ties,
        // matching jnp.argmin's first-min rule.
#pragma unroll
        for (int j = 0; j < 8; j++) {
            const int code = nb + tw * 8 + j;
#pragma unroll
            for (int i = 0; i < 8; i++) {
                if (acc[i][j] > best_val[i]) { best_val[i] = acc[i][j]; best_idx[i] = code; }
            }
        }
    }

    // cross-thread reduction over the 16 code groups per token.
    __syncthreads();
    float* red_v = &As[0][0];          // 128*16 = 2048 floats, fits
    int*   red_i = reinterpret_cast<int*>(&Bs[0][0]);
#pragma unroll
    for (int i = 0; i < 8; i++) {
        const int token = tm * 8 + i;
        red_v[token * 16 + tw] = best_val[i];
        red_i[token * 16 + tw] = best_idx[i];
    }
    __syncthreads();
    if (t < MT) {
        float bv = red_v[t * 16];
        int   bi = red_i[t * 16];
#pragma unroll 1
        for (int w = 1; w < 16; w++) {
            const float v = red_v[t * 16 + w];
            const int   ii = red_i[t * 16 + w];
            if (v > bv || (v == bv && ii < bi)) { bv = v; bi = ii; }
        }
        idx_out[tok_base + t] = bi;
    }
}

// --------------------------------------------------------------------------
// K3: loss partial sums + pos-mask scatter. Block = 64 tokens x 256 dims.
// --------------------------------------------------------------------------
__global__ void k_loss(const float* __restrict__ z, const float* __restrict__ W,
                       const int* __restrict__ idx, int* __restrict__ mask,
                       double* __restrict__ lacc) {
    const int t = threadIdx.x;             // 256
    const int tok0 = blockIdx.x * 64;      // 1024 blocks
    float acc = 0.0f;
#pragma unroll 4
    for (int i = 0; i < 64; i++) {
        const int tok = tok0 + i;
        const int e = idx[tok];
        const float d = z[(size_t)tok * E_DIM + t] - W[(size_t)e * E_DIM + t];
        acc = fmaf(d, d, acc);
        if (t == 0) mask[e] = 1;           // benign race: everyone writes 1
    }
    __shared__ float red[256];
    red[t] = acc;
    __syncthreads();
#pragma unroll
    for (int s2 = 128; s2 > 0; s2 >>= 1) {
        if (t < s2) red[t] += red[t + s2];
        __syncthreads();
    }
    if (t == 0) atomicAdd(lacc, (double)red[0]);
}

// --------------------------------------------------------------------------
// K4: 1-block prefix scan over mask -> rank (stable pos-first order),
// plus loss finalize.
// --------------------------------------------------------------------------
__global__ void k_scan(const int* __restrict__ mask, int* __restrict__ rank,
                       const double* __restrict__ lacc, float* __restrict__ loss_out) {
    __shared__ int buf[N_E];
    const int t = threadIdx.x;             // 1024
    const int m = mask[t];
    buf[t] = m;
    __syncthreads();
    for (int off = 1; off < N_E; off <<= 1) {
        const int v = (t >= off) ? buf[t - off] : 0;
        __syncthreads();
        buf[t] += v;
        __syncthreads();
    }
    const int incl  = buf[t];
    const int total = buf[N_E - 1];
    rank[t] = m ? (incl - m) : (total + t - (incl - m));
    if (t == 0) {
        const double mse = (*lacc) / (double)((size_t)N_TOK * E_DIM);
        *loss_out = (float)((1.0 + (double)BETA) * mse);
    }
}

// --------------------------------------------------------------------------
// K5: emb[rank[e]] = W[e]; label[rank[e]] = mask[e].
// --------------------------------------------------------------------------
__global__ void k_emit(const float* __restrict__ W, const int* __restrict__ rank,
                       const int* __restrict__ mask, float* __restrict__ out) {
    const int e = blockIdx.x;              // 1024
    const int t = threadIdx.x;             // 256
    const int r = rank[e];
    out[(size_t)r * E_DIM + t] = W[(size_t)e * E_DIM + t];
    if (t == 0) out[(size_t)N_E * E_DIM + r] = mask[e] ? 1.0f : 0.0f;
}

// --------------------------------------------------------------------------
extern "C" void kernel_launch(void* const* d_in, const int* in_sizes, int n_in,
                              void* d_out, int out_size, void* d_ws, size_t ws_size,
                              hipStream_t stream) {
    const float* z = (const float*)d_in[0];
    const float* W = (const float*)d_in[1];
    float* out = (float*)d_out;
    char* ws = (char*)d_ws;

    float*  inv_norm = (float*)(ws + WS_INVNORM);
    int*    idx      = (int*)(ws + WS_IDX);
    int*    mask     = (int*)(ws + WS_MASK);
    int*    rank     = (int*)(ws + WS_RANK);
    double* lacc     = (double*)(ws + WS_LACC);

    float* loss_out = out + (size_t)N_E * E_DIM + N_E;  // 263168

    k_norms <<<N_E, 64, 0, stream>>>(W, inv_norm, mask, lacc);
    k_argmax<<<N_TOK / MT, 256, 0, stream>>>(z, W, inv_norm, idx);
    k_loss  <<<N_TOK / 64, 256, 0, stream>>>(z, W, idx, mask, lacc);
    k_scan  <<<1, N_E, 0, stream>>>(mask, rank, lacc, loss_out);
    k_emit  <<<N_E, 256, 0, stream>>>(W, rank, mask, out);
}